// Round 5
// baseline (799.972 us; speedup 1.0000x reference)
//
#include <hip/hip_runtime.h>

// Codred forward. R4:
//  - gemm128: 128x128 tile, BK=32, 4 waves x (4x4) 16x16x32 MFMA, global_load_lds
//    width=16, double-buffered LDS (2-phase: STAGE(next) -> compute(cur) -> 1 barrier)
//  - gemm_uv replaced by bf16 MFMA gemm over concat [wu|wvv] (M=40), htb cast bf16
//  - all per-layer weight transposes fused into one z=6 launch; upfront z=3
//  - attention: flash-decoding NS=3 (unchanged from R3)

#define D    768
#define H    8
#define DKD  96
#define LAY  4
#define FFD  1024
#define NREL 97
#define BAG  8
#define SPANS 5
#define E    40
#define TT   1600
#define SEQ  512
#define D3   2304   // fused qkv width
#define NS   3      // kv chunks

typedef __attribute__((ext_vector_type(8))) short bf16x8;
typedef __attribute__((ext_vector_type(4))) float f32x4;
typedef unsigned short ushort_t;
typedef unsigned int uint_t;

__device__ __forceinline__ ushort_t f2b(float x) {
    uint_t u = __builtin_bit_cast(uint_t, x);
    return (ushort_t)((u + 0x7fffu + ((u >> 16) & 1u)) >> 16);   // RNE
}
__device__ __forceinline__ float b2f(ushort_t v) {
    return __builtin_bit_cast(float, (uint_t)v << 16);
}

__device__ __forceinline__ void gload16(const void* g, void* l) {
    __builtin_amdgcn_global_load_lds(
        (const __attribute__((address_space(1))) unsigned int*)g,
        (__attribute__((address_space(3))) unsigned int*)l, 16, 0, 0);
}

// ---------------- block reductions (256 thr) --------------------------------
__device__ __forceinline__ float block_sum(float v, float* red) {
#pragma unroll
    for (int o = 32; o >= 1; o >>= 1) v += __shfl_xor(v, o);
    __syncthreads();
    if ((threadIdx.x & 63) == 0) red[threadIdx.x >> 6] = v;
    __syncthreads();
    return red[0] + red[1] + red[2] + red[3];
}

// ---------------- span max-pool, phase 1: per 64-position group -------------
__global__ __launch_bounds__(256) void span_pool_p1(const float* __restrict__ emb,
        const int* __restrict__ spans, float* __restrict__ partial) {
    const int e = blockIdx.x, pg = blockIdx.y;
    const int bag = e / SPANS;
    const int st = spans[e * 2 + 0];
    const int en = spans[e * 2 + 1];
    const int p0 = max(st, pg * 64);
    const int p1 = min(en, pg * 64 + 63);
    const int tid = threadIdx.x;
    if (tid >= 192) return;
    float4 m = make_float4(-1e30f, -1e30f, -1e30f, -1e30f);
    for (int p = p0; p <= p1; ++p) {
        const float4 v = *(const float4*)(emb + ((size_t)bag * SEQ + p) * D + tid * 4);
        m.x = fmaxf(m.x, v.x); m.y = fmaxf(m.y, v.y);
        m.z = fmaxf(m.z, v.z); m.w = fmaxf(m.w, v.w);
    }
    *(float4*)(partial + ((size_t)e * 8 + pg) * D + tid * 4) = m;
}

// ---------------- span max-pool, phase 2: reduce 8 partials -> bf16 htb -----
__global__ __launch_bounds__(256) void span_pool_p2(const float* __restrict__ partial,
        ushort_t* __restrict__ htb) {
    const int e = blockIdx.x;
    const int tid = threadIdx.x;
    if (tid >= 192) return;
    float4 m = make_float4(-1e30f, -1e30f, -1e30f, -1e30f);
#pragma unroll
    for (int pg = 0; pg < 8; ++pg) {
        const float4 v = *(const float4*)(partial + ((size_t)e * 8 + pg) * D + tid * 4);
        m.x = fmaxf(m.x, v.x); m.y = fmaxf(m.y, v.y);
        m.z = fmaxf(m.z, v.z); m.w = fmaxf(m.w, v.w);
    }
    ushort4 o;
    o.x = f2b(m.x); o.y = f2b(m.y); o.z = f2b(m.z); o.w = f2b(m.w);
    *(ushort4*)(htb + (size_t)e * D + tid * 4) = o;
}

// ---------------- alpha: a[ij][d] = relu(u[i][d]+v[j][d]) (bf16 out) --------
// uv layout: [40][1536], u = [:, :768], v = [:, 768:]
__global__ __launch_bounds__(256) void alpha_k(const float* __restrict__ uv,
        ushort_t* __restrict__ a) {
    const int ij = blockIdx.x;
    const int i = ij / E, j = ij % E;
    const int tid = threadIdx.x;
#pragma unroll
    for (int t2 = 0; t2 < 3; ++t2) {
        const int d = tid + t2 * 256;
        a[(size_t)ij * D + d] =
            f2b(fmaxf(uv[(size_t)i * 1536 + d] + uv[(size_t)j * 1536 + 768 + d], 0.f));
    }
}

// ---------------- upfront transpose: z=0 lnr->lnrT, z=1 wu, z=2 wvv -> wuvT -
__global__ __launch_bounds__(256) void transpose_up(const float* __restrict__ lnr,
        const float* __restrict__ wu, const float* __restrict__ wvv,
        ushort_t* __restrict__ lnrT, ushort_t* __restrict__ wuvT) {
    __shared__ float t[32][33];
    const int z = blockIdx.z;
    const float* src = (z == 0) ? lnr : (z == 1) ? wu : wvv;
    ushort_t* dst = (z == 0) ? lnrT : wuvT + (size_t)(z - 1) * D * D;
    const int n0 = blockIdx.x * 32, k0 = blockIdx.y * 32;
    const int tx = threadIdx.x & 31, ty = threadIdx.x >> 5;
#pragma unroll
    for (int i = 0; i < 4; ++i)
        t[ty + i * 8][tx] = src[(size_t)(k0 + ty + i * 8) * D + n0 + tx];
    __syncthreads();
#pragma unroll
    for (int i = 0; i < 4; ++i)
        dst[(size_t)(n0 + ty + i * 8) * D + k0 + tx] = f2b(t[tx][ty + i * 8]);
}

// ---------------- per-layer fused transpose: z 0..3 wq/wk/wv/wo, 4 w1, 5 w2 -
__global__ __launch_bounds__(256) void transpose_layer(const float* __restrict__ wq,
        const float* __restrict__ wk, const float* __restrict__ wv,
        const float* __restrict__ wo, const float* __restrict__ w1,
        const float* __restrict__ w2, int l, ushort_t* __restrict__ wT4,
        ushort_t* __restrict__ w1T, ushort_t* __restrict__ w2T) {
    __shared__ float t[32][33];
    const int z = blockIdx.z;
    const float* src; ushort_t* dst; int K, N;
    if (z < 4) {
        K = D; N = D;
        src = (z == 0 ? wq : z == 1 ? wk : z == 2 ? wv : wo) + (size_t)l * D * D;
        dst = wT4 + (size_t)z * D * D;
    } else if (z == 4) {
        K = D; N = FFD; src = w1 + (size_t)l * D * FFD; dst = w1T;
    } else {
        K = FFD; N = D; src = w2 + (size_t)l * FFD * D; dst = w2T;
    }
    const int n0 = blockIdx.x * 32, k0 = blockIdx.y * 32;
    if (n0 >= N || k0 >= K) return;
    const int tx = threadIdx.x & 31, ty = threadIdx.x >> 5;
#pragma unroll
    for (int i = 0; i < 4; ++i)
        t[ty + i * 8][tx] = src[(size_t)(k0 + ty + i * 8) * N + n0 + tx];
    __syncthreads();
#pragma unroll
    for (int i = 0; i < 4; ++i)
        dst[(size_t)(n0 + ty + i * 8) * K + k0 + tx] = f2b(t[tx][ty + i * 8]);
}

// ---------------- biases: bqkv [L][2304], buv [1536] -------------------------
__global__ __launch_bounds__(256) void concat_bias(const float* __restrict__ bq,
        const float* __restrict__ bk, const float* __restrict__ bv,
        const float* __restrict__ bu, const float* __restrict__ bvv,
        float* __restrict__ bqkv, float* __restrict__ buv) {
    const int i = blockIdx.x * 256 + threadIdx.x;
    if (i < LAY * D3) {
        const int l = i / D3, j = i % D3;
        bqkv[i] = j < D ? bq[l * D + j] : j < 2 * D ? bk[l * D + j - D] : bv[l * D + j - 2 * D];
    }
    const int k = i - LAY * D3;
    if (k >= 0 && k < 2 * D) buv[k] = k < D ? bu[k] : bvv[k - D];
}

// ---------------- bf16 MFMA GEMM: C = A[M,K] @ Bt[N,K]^T + bias -------------
// 128x128 tile, BK=32, 4 waves (2x2), per wave 4x4 frags. Double-buffered LDS,
// global_load_lds width=16, one __syncthreads per K-step (T3-minimum 2-phase).
template<int RELU>
__global__ __launch_bounds__(256) void gemm128(const ushort_t* __restrict__ A,
        const ushort_t* __restrict__ Bt, const float* __restrict__ bias,
        float* __restrict__ Cf, ushort_t* __restrict__ Cb, int M, int N, int K) {
    __shared__ ushort_t As[2][128 * 32];   // linear: row*32 + col
    __shared__ ushort_t Bs[2][128 * 32];
    const int tid = threadIdx.x;
    const int lane = tid & 63, w = tid >> 6;
    const int l15 = lane & 15, lg = lane >> 4;
    const int bm = blockIdx.y * 128, bn = blockIdx.x * 128;
    const int wm = (w >> 1) * 64, wn = (w & 1) * 64;
    // staging: wave w covers rows [w*32, w*32+32) of both tiles via 2 instrs each
    const int srow = lane >> 2;            // 0..15
    const int scol = (lane & 3) * 8;       // ushort col within BK=32
    const int rA0 = w * 32 + srow, rA1 = rA0 + 16;
    const size_t gA0 = (size_t)min(bm + rA0, M - 1) * K + scol;
    const size_t gA1 = (size_t)min(bm + rA1, M - 1) * K + scol;
    const size_t gB0 = (size_t)min(bn + rA0, N - 1) * K + scol;
    const size_t gB1 = (size_t)min(bn + rA1, N - 1) * K + scol;

    f32x4 acc[4][4];
#pragma unroll
    for (int mi = 0; mi < 4; ++mi)
#pragma unroll
        for (int ni = 0; ni < 4; ++ni)
            acc[mi][ni] = (f32x4){0.f, 0.f, 0.f, 0.f};

    auto STAGE = [&](int buf, int k0) {
        gload16(A + gA0 + k0, &As[buf][w * 1024]);
        gload16(A + gA1 + k0, &As[buf][w * 1024 + 512]);
        gload16(Bt + gB0 + k0, &Bs[buf][w * 1024]);
        gload16(Bt + gB1 + k0, &Bs[buf][w * 1024 + 512]);
    };

    const int nt = K / 32;
    STAGE(0, 0);
    __syncthreads();                       // drain vmcnt: buf0 ready
    for (int t = 0; t < nt; ++t) {
        const int buf = t & 1;
        if (t + 1 < nt) STAGE(buf ^ 1, (t + 1) * 32);
        bf16x8 af[4], bfr[4];
#pragma unroll
        for (int mi = 0; mi < 4; ++mi)
            af[mi] = *(const bf16x8*)&As[buf][(wm + mi * 16 + l15) * 32 + lg * 8];
#pragma unroll
        for (int ni = 0; ni < 4; ++ni)
            bfr[ni] = *(const bf16x8*)&Bs[buf][(wn + ni * 16 + l15) * 32 + lg * 8];
        __builtin_amdgcn_s_setprio(1);
#pragma unroll
        for (int mi = 0; mi < 4; ++mi)
#pragma unroll
            for (int ni = 0; ni < 4; ++ni)
                acc[mi][ni] = __builtin_amdgcn_mfma_f32_16x16x32_bf16(
                    af[mi], bfr[ni], acc[mi][ni], 0, 0, 0);
        __builtin_amdgcn_s_setprio(0);
        __syncthreads();                   // drains STAGE(next) + barrier
    }
#pragma unroll
    for (int mi = 0; mi < 4; ++mi)
#pragma unroll
        for (int ni = 0; ni < 4; ++ni)
#pragma unroll
            for (int r = 0; r < 4; ++r) {
                const int row = bm + wm + mi * 16 + lg * 4 + r;
                if (row >= M) continue;
                const int col = bn + wn + ni * 16 + l15;
                float v = acc[mi][ni][r] + bias[col];
                if (RELU) v = fmaxf(v, 0.f);
                if (Cf) Cf[(size_t)row * N + col] = v;
                if (Cb) Cb[(size_t)row * N + col] = f2b(v);
            }
}

// ---------------- flash-decoding attention, partial over a KV chunk ---------
__global__ __launch_bounds__(256) void attn_part(const ushort_t* __restrict__ Q,
        const ushort_t* __restrict__ K, const ushort_t* __restrict__ V,
        ushort_t* __restrict__ Opart, float* __restrict__ ml, int ldin) {
    __shared__ ushort_t Qs[64][104];     // 96 + 8 pad
    __shared__ ushort_t Ks[64][104];
    __shared__ ushort_t Vt[96][76];      // transposed V, +4 pad
    __shared__ ushort_t Ps[4][16][72];   // per-wave P tile
    const int q0 = blockIdx.x * 64;
    const int h = blockIdx.y;
    const int cch = blockIdx.z;
    const int t_lo = (cch * (TT / 64)) / NS;
    const int t_hi = ((cch + 1) * (TT / 64)) / NS;
    const int tid = threadIdx.x;
    const int lane = tid & 63, w = tid >> 6;
    const int l15 = lane & 15, lg = lane >> 4;
    const float scale = 0.10206207261596577f;   // 1/sqrt(96)

    int r_[3], c_[3];
#pragma unroll
    for (int i = 0; i < 3; ++i) {
        const int ch = i * 256 + tid;
        r_[i] = ch / 12; c_[i] = (ch % 12) * 8;
    }
#pragma unroll
    for (int i = 0; i < 3; ++i) {
        const uint4 v4 = *(const uint4*)(Q + (size_t)(q0 + r_[i]) * ldin + h * DKD + c_[i]);
        *(uint4*)&Qs[r_[i]][c_[i]] = v4;
    }
    uint4 kreg[3], vreg[3];
    {
        const int s0 = t_lo * 64;
#pragma unroll
        for (int i = 0; i < 3; ++i) {
            kreg[i] = *(const uint4*)(K + (size_t)(s0 + r_[i]) * ldin + h * DKD + c_[i]);
            vreg[i] = *(const uint4*)(V + (size_t)(s0 + r_[i]) * ldin + h * DKD + c_[i]);
        }
    }
    float m_run[4], l_run[4];
    f32x4 acc_o[6];
#pragma unroll
    for (int r = 0; r < 4; ++r) { m_run[r] = -1e30f; l_run[r] = 0.f; }
#pragma unroll
    for (int nt = 0; nt < 6; ++nt) acc_o[nt] = (f32x4){0.f, 0.f, 0.f, 0.f};

    for (int t = t_lo; t < t_hi; ++t) {
        __syncthreads();
#pragma unroll
        for (int i = 0; i < 3; ++i) {
            *(uint4*)&Ks[r_[i]][c_[i]] = kreg[i];
            const ushort_t* pv = (const ushort_t*)&vreg[i];
#pragma unroll
            for (int j = 0; j < 8; ++j) Vt[c_[i] + j][r_[i]] = pv[j];
        }
        __syncthreads();
        if (t + 1 < t_hi) {
            const int s0 = (t + 1) * 64;
#pragma unroll
            for (int i = 0; i < 3; ++i) {
                kreg[i] = *(const uint4*)(K + (size_t)(s0 + r_[i]) * ldin + h * DKD + c_[i]);
                vreg[i] = *(const uint4*)(V + (size_t)(s0 + r_[i]) * ldin + h * DKD + c_[i]);
            }
        }
        f32x4 accs[4];
#pragma unroll
        for (int ni = 0; ni < 4; ++ni) accs[ni] = (f32x4){0.f, 0.f, 0.f, 0.f};
        __builtin_amdgcn_s_setprio(1);
#pragma unroll
        for (int ks = 0; ks < 3; ++ks) {
            const bf16x8 aq = *(const bf16x8*)&Qs[w * 16 + l15][ks * 32 + lg * 8];
#pragma unroll
            for (int ni = 0; ni < 4; ++ni) {
                const bf16x8 bk = *(const bf16x8*)&Ks[ni * 16 + l15][ks * 32 + lg * 8];
                accs[ni] = __builtin_amdgcn_mfma_f32_16x16x32_bf16(aq, bk, accs[ni], 0, 0, 0);
            }
        }
        __builtin_amdgcn_s_setprio(0);
        float ps[4][4];
#pragma unroll
        for (int r = 0; r < 4; ++r) {
#pragma unroll
            for (int ni = 0; ni < 4; ++ni) ps[ni][r] = accs[ni][r] * scale;
            float mx = fmaxf(fmaxf(ps[0][r], ps[1][r]), fmaxf(ps[2][r], ps[3][r]));
#pragma unroll
            for (int o = 1; o <= 8; o <<= 1) mx = fmaxf(mx, __shfl_xor(mx, o));
            const float mnew = fmaxf(m_run[r], mx);
            const float sf = __expf(m_run[r] - mnew);
            m_run[r] = mnew;
            float rs = 0.f;
#pragma unroll
            for (int ni = 0; ni < 4; ++ni) {
                ps[ni][r] = __expf(ps[ni][r] - mnew);
                rs += ps[ni][r];
            }
#pragma unroll
            for (int o = 1; o <= 8; o <<= 1) rs += __shfl_xor(rs, o);
            l_run[r] = l_run[r] * sf + rs;
#pragma unroll
            for (int nt = 0; nt < 6; ++nt) acc_o[nt][r] *= sf;
        }
#pragma unroll
        for (int ni = 0; ni < 4; ++ni)
#pragma unroll
            for (int r = 0; r < 4; ++r)
                Ps[w][lg * 4 + r][ni * 16 + l15] = f2b(ps[ni][r]);
        __builtin_amdgcn_s_setprio(1);
#pragma unroll
        for (int ks = 0; ks < 2; ++ks) {
            const bf16x8 ap = *(const bf16x8*)&Ps[w][l15][ks * 32 + lg * 8];
#pragma unroll
            for (int nt = 0; nt < 6; ++nt) {
                const bf16x8 bv = *(const bf16x8*)&Vt[nt * 16 + l15][ks * 32 + lg * 8];
                acc_o[nt] = __builtin_amdgcn_mfma_f32_16x16x32_bf16(ap, bv, acc_o[nt], 0, 0, 0);
            }
        }
        __builtin_amdgcn_s_setprio(0);
    }
#pragma unroll
    for (int nt = 0; nt < 6; ++nt)
#pragma unroll
        for (int r = 0; r < 4; ++r) {
            const int row = q0 + w * 16 + lg * 4 + r;
            const int col = h * DKD + nt * 16 + l15;
            Opart[((size_t)cch * TT + row) * D + col] = f2b(acc_o[nt][r]);
        }
    if (l15 == 0) {
#pragma unroll
        for (int r = 0; r < 4; ++r) {
            const int row = q0 + w * 16 + lg * 4 + r;
            float2* mlp = (float2*)ml;
            mlp[((size_t)cch * H + h) * TT + row] = make_float2(m_run[r], l_run[r]);
        }
    }
}

// ---------------- combine NS partials per row -------------------------------
__global__ __launch_bounds__(256) void attn_combine(const ushort_t* __restrict__ Opart,
        const float* __restrict__ ml, ushort_t* __restrict__ O) {
    const int row = blockIdx.x;
    const int tid = threadIdx.x;
    const float2* mlp = (const float2*)ml;
#pragma unroll
    for (int kk = 0; kk < 3; ++kk) {
        const int col = tid + kk * 256;
        const int h = col / DKD;
        float m[NS], l[NS], M = -1e30f;
#pragma unroll
        for (int c = 0; c < NS; ++c) {
            const float2 v = mlp[((size_t)c * H + h) * TT + row];
            m[c] = v.x; l[c] = v.y; M = fmaxf(M, m[c]);
        }
        float L = 0.f, o = 0.f;
#pragma unroll
        for (int c = 0; c < NS; ++c) {
            const float e = __expf(m[c] - M);
            L += l[c] * e;
            o += b2f(Opart[((size_t)c * TT + row) * D + col]) * e;
        }
        O[(size_t)row * D + col] = f2b(o / L);
    }
}

// ---------------- x = LN(x + y); writes fp32 x and bf16 xb ------------------
__global__ __launch_bounds__(256) void add_ln(float* __restrict__ x,
        const float* __restrict__ y, const float* __restrict__ g,
        const float* __restrict__ b, ushort_t* __restrict__ xb) {
    __shared__ float red[4];
    const int row = blockIdx.x;
    const int tid = threadIdx.x;
    float vals[3];
    float s = 0.f;
#pragma unroll
    for (int i = 0; i < 3; ++i) {
        const int c = tid + i * 256;
        const float t = x[(size_t)row * D + c] + y[(size_t)row * D + c];
        vals[i] = t; s += t;
    }
    const float mean = block_sum(s, red) * (1.f / 768.f);
    float s2 = 0.f;
#pragma unroll
    for (int i = 0; i < 3; ++i) { const float dd = vals[i] - mean; s2 += dd * dd; }
    const float var = block_sum(s2, red) * (1.f / 768.f);
    const float inv = rsqrtf(var + 1e-5f);
#pragma unroll
    for (int i = 0; i < 3; ++i) {
        const int c = tid + i * 256;
        const float o = (vals[i] - mean) * inv * g[c] + b[c];
        x[(size_t)row * D + c] = o;
        xb[(size_t)row * D + c] = f2b(o);
    }
}

// ---------------- predictor -------------------------------------------------
__global__ __launch_bounds__(256) void predict_k(const float* __restrict__ x,
        const float* __restrict__ pw, const float* __restrict__ pb,
        float* __restrict__ out) {
    __shared__ float red[4];
    const int r = blockIdx.x;
    const int tid = threadIdx.x;
    float best = -1e30f;
    for (int bag = 0; bag < BAG; ++bag) {
        const int row = (bag * SPANS) * E + (bag * SPANS + 1);
        const float* f = x + (size_t)row * D;
        float acc = 0.f;
        for (int d = tid; d < D; d += 256) acc += f[d] * pw[(size_t)d * NREL + r];
        best = fmaxf(best, block_sum(acc, red));
    }
    if (tid == 0) out[r] = best + pb[r];
}

extern "C" void kernel_launch(void* const* d_in, const int* in_sizes, int n_in,
                              void* d_out, int out_size, void* d_ws, size_t ws_size,
                              hipStream_t stream) {
    const float* emb  = (const float*)d_in[0];
    const int*  spans = (const int*)d_in[1];
    const float* wu_w = (const float*)d_in[2];  const float* wu_b = (const float*)d_in[3];
    const float* wvv_w= (const float*)d_in[4];  const float* wvv_b= (const float*)d_in[5];
    const float* lnr_w= (const float*)d_in[6];  const float* lnr_b= (const float*)d_in[7];
    const float* wq = (const float*)d_in[8];    const float* bq = (const float*)d_in[9];
    const float* wk = (const float*)d_in[10];   const float* bk = (const float*)d_in[11];
    const float* wv = (const float*)d_in[12];   const float* bv = (const float*)d_in[13];
    const float* wo = (const float*)d_in[14];   const float* bo = (const float*)d_in[15];
    const float* w1 = (const float*)d_in[16];   const float* b1 = (const float*)d_in[17];
    const float* w2 = (const float*)d_in[18];   const float* b2 = (const float*)d_in[19];
    const float* g1 = (const float*)d_in[20];   const float* be1= (const float*)d_in[21];
    const float* g2 = (const float*)d_in[22];   const float* be2= (const float*)d_in[23];
    const float* pw = (const float*)d_in[24];   const float* pb = (const float*)d_in[25];

    // workspace layout (~36 MB). tb/fb adjacency required (Opart alias).
    char* cur = (char*)d_ws;
    auto alloc = [&](size_t bytes) { char* p = cur; cur += (bytes + 255) & ~(size_t)255; return p; };
    ushort_t* htb  = (ushort_t*)alloc(E * D * 2);
    float*    uvb  = (float*)alloc((size_t)E * 1536 * 4);
    float*    part = (float*)alloc((size_t)E * 8 * D * 4);   // span partials; reused as ml
    float*    x    = (float*)alloc((size_t)TT * D * 4);
    ushort_t* xb   = (ushort_t*)alloc((size_t)TT * D * 2);
    ushort_t* qkv  = (ushort_t*)alloc((size_t)TT * D3 * 2);
    ushort_t* ob   = (ushort_t*)alloc((size_t)TT * D * 2);   // alpha, then attn out
    float*    tb   = (float*)alloc((size_t)TT * D * 4);      // adjacent ...
    ushort_t* fb   = (ushort_t*)alloc((size_t)TT * FFD * 2); // ... to tb
    ushort_t* wT4  = (ushort_t*)alloc((size_t)4 * D * D * 2);
    ushort_t* w1T  = (ushort_t*)alloc((size_t)D * FFD * 2);
    ushort_t* w2T  = (ushort_t*)alloc((size_t)FFD * D * 2);
    float*    bqkv = (float*)alloc((size_t)LAY * D3 * 4);
    float*    buv  = (float*)alloc((size_t)2 * D * 4);
    ushort_t* Opart = (ushort_t*)tb;    // NS*TT*D*2 = 7.37 MB <= tb+fb
    float*    ml    = part;             // 300 KB <= part
    ushort_t* wuvT  = wT4;              // [1536][768] bf16, used before layer 0
    ushort_t* lnrT  = w1T;              // [768][768] bf16, used before layer 0

    const int DD = D * D;

    span_pool_p1<<<dim3(E, 8), 256, 0, stream>>>(emb, spans, part);
    span_pool_p2<<<E, 256, 0, stream>>>(part, htb);
    transpose_up<<<dim3(24, 24, 3), 256, 0, stream>>>(lnr_w, wu_w, wvv_w, lnrT, wuvT);
    concat_bias<<<(LAY * D3 + 2 * D + 255) / 256, 256, 0, stream>>>(bq, bk, bv, wu_b, wvv_b, bqkv, buv);
    gemm128<0><<<dim3(1536 / 128, 1), 256, 0, stream>>>(htb, wuvT, buv, uvb, nullptr, E, 1536, D);
    alpha_k<<<TT, 256, 0, stream>>>(uvb, ob);
    gemm128<1><<<dim3(D / 128, (TT + 127) / 128), 256, 0, stream>>>(ob, lnrT, lnr_b, x, xb, TT, D, D);

    for (int l = 0; l < LAY; ++l) {
        transpose_layer<<<dim3(32, 32, 6), 256, 0, stream>>>(wq, wk, wv, wo, w1, w2, l, wT4, w1T, w2T);
        gemm128<0><<<dim3(D3 / 128, (TT + 127) / 128), 256, 0, stream>>>(
            xb, wT4, bqkv + l * D3, nullptr, qkv, TT, D3, D);
        attn_part<<<dim3(TT / 64, H, NS), 256, 0, stream>>>(
            qkv, qkv + D, qkv + 2 * D, Opart, ml, D3);
        attn_combine<<<TT, 256, 0, stream>>>(Opart, ml, ob);
        gemm128<0><<<dim3(D / 128, (TT + 127) / 128), 256, 0, stream>>>(
            ob, wT4 + 3 * DD, bo + l * D, tb, nullptr, TT, D, D);
        add_ln<<<TT, 256, 0, stream>>>(x, tb, g1 + l * D, be1 + l * D, xb);
        gemm128<1><<<dim3(FFD / 128, (TT + 127) / 128), 256, 0, stream>>>(
            xb, w1T, b1 + l * FFD, nullptr, fb, TT, FFD, D);
        gemm128<0><<<dim3(D / 128, (TT + 127) / 128), 256, 0, stream>>>(
            fb, w2T, b2 + l * D, tb, nullptr, TT, D, FFD);
        add_ln<<<TT, 256, 0, stream>>>(x, tb, g2 + l * D, be2 + l * D, xb);
    }

    predict_k<<<NREL, 256, 0, stream>>>(x, pw, pb, (float*)d_out);
    (void)in_sizes; (void)n_in; (void)out_size; (void)ws_size;
}

// Round 6
// 771.137 us; speedup vs baseline: 1.0374x; 1.0374x over previous
//
#include <hip/hip_runtime.h>

// Codred forward. R5:
//  - GEMM reverted to proven R3 structure (128x64, single-buffer, global_load_lds);
//    R4's 128x128 dbuf starved the grid (78 blocks/256 CUs) -> regression
//  - V produced pre-transposed by swapped-operand GEMM (vT = wvT @ xb^T, row-bias);
//    attention stages V^T with uint4 copies -> no in-kernel transpose, conflicts gone
//  - QKV projection is now QK-only (N=1536); attn reads Q,K (ld=1536) + vT rows
//  - kept: MFMA uv-GEMM, fused per-layer transposes, flash-decoding NS=3

#define D    768
#define H    8
#define DKD  96
#define LAY  4
#define FFD  1024
#define NREL 97
#define BAG  8
#define SPANS 5
#define E    40
#define TT   1600
#define SEQ  512
#define D2   1536   // fused qk width
#define NS   3      // kv chunks

typedef __attribute__((ext_vector_type(8))) short bf16x8;
typedef __attribute__((ext_vector_type(4))) float f32x4;
typedef unsigned short ushort_t;
typedef unsigned int uint_t;

__device__ __forceinline__ ushort_t f2b(float x) {
    uint_t u = __builtin_bit_cast(uint_t, x);
    return (ushort_t)((u + 0x7fffu + ((u >> 16) & 1u)) >> 16);   // RNE
}
__device__ __forceinline__ float b2f(ushort_t v) {
    return __builtin_bit_cast(float, (uint_t)v << 16);
}

__device__ __forceinline__ void gload16(const void* g, void* l) {
    __builtin_amdgcn_global_load_lds(
        (const __attribute__((address_space(1))) unsigned int*)g,
        (__attribute__((address_space(3))) unsigned int*)l, 16, 0, 0);
}

// ---------------- block reductions (256 thr) --------------------------------
__device__ __forceinline__ float block_sum(float v, float* red) {
#pragma unroll
    for (int o = 32; o >= 1; o >>= 1) v += __shfl_xor(v, o);
    __syncthreads();
    if ((threadIdx.x & 63) == 0) red[threadIdx.x >> 6] = v;
    __syncthreads();
    return red[0] + red[1] + red[2] + red[3];
}

// ---------------- span max-pool, phase 1 ------------------------------------
__global__ __launch_bounds__(256) void span_pool_p1(const float* __restrict__ emb,
        const int* __restrict__ spans, float* __restrict__ partial) {
    const int e = blockIdx.x, pg = blockIdx.y;
    const int bag = e / SPANS;
    const int st = spans[e * 2 + 0];
    const int en = spans[e * 2 + 1];
    const int p0 = max(st, pg * 64);
    const int p1 = min(en, pg * 64 + 63);
    const int tid = threadIdx.x;
    if (tid >= 192) return;
    float4 m = make_float4(-1e30f, -1e30f, -1e30f, -1e30f);
    for (int p = p0; p <= p1; ++p) {
        const float4 v = *(const float4*)(emb + ((size_t)bag * SEQ + p) * D + tid * 4);
        m.x = fmaxf(m.x, v.x); m.y = fmaxf(m.y, v.y);
        m.z = fmaxf(m.z, v.z); m.w = fmaxf(m.w, v.w);
    }
    *(float4*)(partial + ((size_t)e * 8 + pg) * D + tid * 4) = m;
}

// ---------------- span max-pool, phase 2 -> bf16 htb ------------------------
__global__ __launch_bounds__(256) void span_pool_p2(const float* __restrict__ partial,
        ushort_t* __restrict__ htb) {
    const int e = blockIdx.x;
    const int tid = threadIdx.x;
    if (tid >= 192) return;
    float4 m = make_float4(-1e30f, -1e30f, -1e30f, -1e30f);
#pragma unroll
    for (int pg = 0; pg < 8; ++pg) {
        const float4 v = *(const float4*)(partial + ((size_t)e * 8 + pg) * D + tid * 4);
        m.x = fmaxf(m.x, v.x); m.y = fmaxf(m.y, v.y);
        m.z = fmaxf(m.z, v.z); m.w = fmaxf(m.w, v.w);
    }
    ushort4 o;
    o.x = f2b(m.x); o.y = f2b(m.y); o.z = f2b(m.z); o.w = f2b(m.w);
    *(ushort4*)(htb + (size_t)e * D + tid * 4) = o;
}

// ---------------- alpha: a[ij][d] = relu(u[i][d]+v[j][d]) (bf16 out) --------
__global__ __launch_bounds__(256) void alpha_k(const float* __restrict__ uv,
        ushort_t* __restrict__ a) {
    const int ij = blockIdx.x;
    const int i = ij / E, j = ij % E;
    const int tid = threadIdx.x;
#pragma unroll
    for (int t2 = 0; t2 < 3; ++t2) {
        const int d = tid + t2 * 256;
        a[(size_t)ij * D + d] =
            f2b(fmaxf(uv[(size_t)i * 1536 + d] + uv[(size_t)j * 1536 + 768 + d], 0.f));
    }
}

// ---------------- upfront transpose: z=0 lnr, z=1 wu, z=2 wvv ---------------
__global__ __launch_bounds__(256) void transpose_up(const float* __restrict__ lnr,
        const float* __restrict__ wu, const float* __restrict__ wvv,
        ushort_t* __restrict__ lnrT, ushort_t* __restrict__ wuvT) {
    __shared__ float t[32][33];
    const int z = blockIdx.z;
    const float* src = (z == 0) ? lnr : (z == 1) ? wu : wvv;
    ushort_t* dst = (z == 0) ? lnrT : wuvT + (size_t)(z - 1) * D * D;
    const int n0 = blockIdx.x * 32, k0 = blockIdx.y * 32;
    const int tx = threadIdx.x & 31, ty = threadIdx.x >> 5;
#pragma unroll
    for (int i = 0; i < 4; ++i)
        t[ty + i * 8][tx] = src[(size_t)(k0 + ty + i * 8) * D + n0 + tx];
    __syncthreads();
#pragma unroll
    for (int i = 0; i < 4; ++i)
        dst[(size_t)(n0 + ty + i * 8) * D + k0 + tx] = f2b(t[tx][ty + i * 8]);
}

// ---------------- per-layer fused transpose: z 0..3 wq/wk/wv/wo, 4 w1, 5 w2 -
__global__ __launch_bounds__(256) void transpose_layer(const float* __restrict__ wq,
        const float* __restrict__ wk, const float* __restrict__ wv,
        const float* __restrict__ wo, const float* __restrict__ w1,
        const float* __restrict__ w2, int l, ushort_t* __restrict__ wT4,
        ushort_t* __restrict__ w1T, ushort_t* __restrict__ w2T) {
    __shared__ float t[32][33];
    const int z = blockIdx.z;
    const float* src; ushort_t* dst; int K, N;
    if (z < 4) {
        K = D; N = D;
        src = (z == 0 ? wq : z == 1 ? wk : z == 2 ? wv : wo) + (size_t)l * D * D;
        dst = wT4 + (size_t)z * D * D;
    } else if (z == 4) {
        K = D; N = FFD; src = w1 + (size_t)l * D * FFD; dst = w1T;
    } else {
        K = FFD; N = D; src = w2 + (size_t)l * FFD * D; dst = w2T;
    }
    const int n0 = blockIdx.x * 32, k0 = blockIdx.y * 32;
    if (n0 >= N || k0 >= K) return;
    const int tx = threadIdx.x & 31, ty = threadIdx.x >> 5;
#pragma unroll
    for (int i = 0; i < 4; ++i)
        t[ty + i * 8][tx] = src[(size_t)(k0 + ty + i * 8) * N + n0 + tx];
    __syncthreads();
#pragma unroll
    for (int i = 0; i < 4; ++i)
        dst[(size_t)(n0 + ty + i * 8) * K + k0 + tx] = f2b(t[tx][ty + i * 8]);
}

// ---------------- biases: bqk [L][1536], buv [1536] --------------------------
__global__ __launch_bounds__(256) void concat_bias(const float* __restrict__ bq,
        const float* __restrict__ bk, const float* __restrict__ bu,
        const float* __restrict__ bvv, float* __restrict__ bqk,
        float* __restrict__ buv) {
    const int i = blockIdx.x * 256 + threadIdx.x;
    if (i < LAY * D2) {
        const int l = i / D2, j = i % D2;
        bqk[i] = j < D ? bq[l * D + j] : bk[l * D + j - D];
    }
    const int k = i - LAY * D2;
    if (k >= 0 && k < 2 * D) buv[k] = k < D ? bu[k] : bvv[k - D];
}

// ---------------- bf16 MFMA GEMM: C = A[M,K] @ Bt[N,K]^T + bias -------------
// 128x64 tile, BK=32, 4 waves (2x2), global_load_lds width=16 (R3 structure).
// ROWBIAS=1: bias indexed by output row (used for the V^T swapped-operand gemm).
template<int RELU, int ROWBIAS>
__global__ __launch_bounds__(256) void gemm_mfma(const ushort_t* __restrict__ A,
        const ushort_t* __restrict__ Bt, const float* __restrict__ bias,
        float* __restrict__ Cf, ushort_t* __restrict__ Cb, int M, int N, int K) {
    __shared__ ushort_t As[128 * 32];   // linear: row*32 + col
    __shared__ ushort_t Bs[64 * 32];
    const int tid = threadIdx.x;
    const int lane = tid & 63, w = tid >> 6;
    const int l15 = lane & 15, lg = lane >> 4;
    const int bm = blockIdx.y * 128, bn = blockIdx.x * 64;
    const int wm = (w >> 1) * 64, wn = (w & 1) * 32;
    const int trA0 = w * 32 + (lane >> 2);
    const int trA1 = trA0 + 16;
    const int trB  = w * 16 + (lane >> 2);
    const int sc   = (lane & 3) * 8;
    const size_t rowA0 = (size_t)min(bm + trA0, M - 1) * K;
    const size_t rowA1 = (size_t)min(bm + trA1, M - 1) * K;
    const size_t rowB  = (size_t)(bn + trB) * K;
    ushort_t* asd0 = As + w * 1024;
    ushort_t* asd1 = As + w * 1024 + 512;
    ushort_t* bsd  = Bs + w * 512;

    f32x4 acc[4][2];
#pragma unroll
    for (int mi = 0; mi < 4; ++mi)
#pragma unroll
        for (int ni = 0; ni < 2; ++ni)
            acc[mi][ni] = (f32x4){0.f, 0.f, 0.f, 0.f};

    for (int k0 = 0; k0 < K; k0 += 32) {
        __syncthreads();
        gload16(A + rowA0 + k0 + sc, asd0);
        gload16(A + rowA1 + k0 + sc, asd1);
        gload16(Bt + rowB + k0 + sc, bsd);
        __syncthreads();
        bf16x8 af[4], bfr[2];
#pragma unroll
        for (int mi = 0; mi < 4; ++mi)
            af[mi] = *(const bf16x8*)&As[(wm + mi * 16 + l15) * 32 + lg * 8];
#pragma unroll
        for (int ni = 0; ni < 2; ++ni)
            bfr[ni] = *(const bf16x8*)&Bs[(wn + ni * 16 + l15) * 32 + lg * 8];
        __builtin_amdgcn_s_setprio(1);
#pragma unroll
        for (int mi = 0; mi < 4; ++mi)
#pragma unroll
            for (int ni = 0; ni < 2; ++ni)
                acc[mi][ni] = __builtin_amdgcn_mfma_f32_16x16x32_bf16(
                    af[mi], bfr[ni], acc[mi][ni], 0, 0, 0);
        __builtin_amdgcn_s_setprio(0);
    }
#pragma unroll
    for (int mi = 0; mi < 4; ++mi)
#pragma unroll
        for (int ni = 0; ni < 2; ++ni)
#pragma unroll
            for (int r = 0; r < 4; ++r) {
                const int row = bm + wm + mi * 16 + lg * 4 + r;
                if (row >= M) continue;
                const int col = bn + wn + ni * 16 + l15;
                float v = acc[mi][ni][r] + (ROWBIAS ? bias[row] : bias[col]);
                if (RELU) v = fmaxf(v, 0.f);
                if (Cf) Cf[(size_t)row * N + col] = v;
                if (Cb) Cb[(size_t)row * N + col] = f2b(v);
            }
}

// ---------------- flash-decoding attention over a KV chunk ------------------
// grid (25 qtiles, 8 heads, NS chunks); 4 waves, wave w owns 16 q-rows.
// Q,K from qk [1600][1536]; V from vT [768][1600] (pre-transposed) -> no
// in-kernel transpose, uint4 staging only.
__global__ __launch_bounds__(256) void attn_part(const ushort_t* __restrict__ qk,
        const ushort_t* __restrict__ vT, ushort_t* __restrict__ Opart,
        float* __restrict__ ml) {
    __shared__ ushort_t Qs[64][104];     // 96 + 8 pad
    __shared__ ushort_t Ks[64][104];
    __shared__ ushort_t VtT[96][72];     // V^T tile: [dim][s], 144B rows
    __shared__ ushort_t Ps[4][16][72];   // per-wave P tile
    const int q0 = blockIdx.x * 64;
    const int h = blockIdx.y;
    const int cch = blockIdx.z;
    const int t_lo = (cch * (TT / 64)) / NS;
    const int t_hi = ((cch + 1) * (TT / 64)) / NS;
    const int tid = threadIdx.x;
    const int lane = tid & 63, w = tid >> 6;
    const int l15 = lane & 15, lg = lane >> 4;
    const float scale = 0.10206207261596577f;   // 1/sqrt(96)

    const ushort_t* Vb = vT + (size_t)h * DKD * TT;

    // chunk coords: K/Q tiles 64 rows x 96 dims; V^T tiles 96 dims x 64 s
    int r_[3], c_[3], vd_[3], vs_[3];
#pragma unroll
    for (int i = 0; i < 3; ++i) {
        const int ch = i * 256 + tid;
        r_[i] = ch / 12; c_[i] = (ch % 12) * 8;
        vd_[i] = ch >> 3; vs_[i] = (ch & 7) * 8;
    }
    // stage Q tile
#pragma unroll
    for (int i = 0; i < 3; ++i) {
        const uint4 v4 = *(const uint4*)(qk + (size_t)(q0 + r_[i]) * D2 + h * DKD + c_[i]);
        *(uint4*)&Qs[r_[i]][c_[i]] = v4;
    }
    // prologue: first K/V^T tile into regs
    uint4 kreg[3], vreg[3];
    {
        const int s0 = t_lo * 64;
#pragma unroll
        for (int i = 0; i < 3; ++i) {
            kreg[i] = *(const uint4*)(qk + (size_t)(s0 + r_[i]) * D2 + D + h * DKD + c_[i]);
            vreg[i] = *(const uint4*)(Vb + (size_t)vd_[i] * TT + s0 + vs_[i]);
        }
    }
    float m_run[4], l_run[4];
    f32x4 acc_o[6];
#pragma unroll
    for (int r = 0; r < 4; ++r) { m_run[r] = -1e30f; l_run[r] = 0.f; }
#pragma unroll
    for (int nt = 0; nt < 6; ++nt) acc_o[nt] = (f32x4){0.f, 0.f, 0.f, 0.f};

    for (int t = t_lo; t < t_hi; ++t) {
        __syncthreads();
#pragma unroll
        for (int i = 0; i < 3; ++i) {
            *(uint4*)&Ks[r_[i]][c_[i]] = kreg[i];
            *(uint4*)&VtT[vd_[i]][vs_[i]] = vreg[i];
        }
        __syncthreads();
        if (t + 1 < t_hi) {            // issue next-tile loads early (T14)
            const int s0 = (t + 1) * 64;
#pragma unroll
            for (int i = 0; i < 3; ++i) {
                kreg[i] = *(const uint4*)(qk + (size_t)(s0 + r_[i]) * D2 + D + h * DKD + c_[i]);
                vreg[i] = *(const uint4*)(Vb + (size_t)vd_[i] * TT + s0 + vs_[i]);
            }
        }
        // S = Q K^T
        f32x4 accs[4];
#pragma unroll
        for (int ni = 0; ni < 4; ++ni) accs[ni] = (f32x4){0.f, 0.f, 0.f, 0.f};
        __builtin_amdgcn_s_setprio(1);
#pragma unroll
        for (int ks = 0; ks < 3; ++ks) {
            const bf16x8 aq = *(const bf16x8*)&Qs[w * 16 + l15][ks * 32 + lg * 8];
#pragma unroll
            for (int ni = 0; ni < 4; ++ni) {
                const bf16x8 bk = *(const bf16x8*)&Ks[ni * 16 + l15][ks * 32 + lg * 8];
                accs[ni] = __builtin_amdgcn_mfma_f32_16x16x32_bf16(aq, bk, accs[ni], 0, 0, 0);
            }
        }
        __builtin_amdgcn_s_setprio(0);
        // online softmax
        float ps[4][4];
#pragma unroll
        for (int r = 0; r < 4; ++r) {
#pragma unroll
            for (int ni = 0; ni < 4; ++ni) ps[ni][r] = accs[ni][r] * scale;
            float mx = fmaxf(fmaxf(ps[0][r], ps[1][r]), fmaxf(ps[2][r], ps[3][r]));
#pragma unroll
            for (int o = 1; o <= 8; o <<= 1) mx = fmaxf(mx, __shfl_xor(mx, o));
            const float mnew = fmaxf(m_run[r], mx);
            const float sf = __expf(m_run[r] - mnew);
            m_run[r] = mnew;
            float rs = 0.f;
#pragma unroll
            for (int ni = 0; ni < 4; ++ni) {
                ps[ni][r] = __expf(ps[ni][r] - mnew);
                rs += ps[ni][r];
            }
#pragma unroll
            for (int o = 1; o <= 8; o <<= 1) rs += __shfl_xor(rs, o);
            l_run[r] = l_run[r] * sf + rs;
#pragma unroll
            for (int nt = 0; nt < 6; ++nt) acc_o[nt][r] *= sf;
        }
#pragma unroll
        for (int ni = 0; ni < 4; ++ni)
#pragma unroll
            for (int r = 0; r < 4; ++r)
                Ps[w][lg * 4 + r][ni * 16 + l15] = f2b(ps[ni][r]);
        // O += P @ V  (B-frag read straight from V^T tile, b128, 2-way max)
        __builtin_amdgcn_s_setprio(1);
#pragma unroll
        for (int ks = 0; ks < 2; ++ks) {
            const bf16x8 ap = *(const bf16x8*)&Ps[w][l15][ks * 32 + lg * 8];
#pragma unroll
            for (int nt = 0; nt < 6; ++nt) {
                const bf16x8 bv = *(const bf16x8*)&VtT[nt * 16 + l15][ks * 32 + lg * 8];
                acc_o[nt] = __builtin_amdgcn_mfma_f32_16x16x32_bf16(ap, bv, acc_o[nt], 0, 0, 0);
            }
        }
        __builtin_amdgcn_s_setprio(0);
    }
    // epilogue: unnormalized O + (m,l)
#pragma unroll
    for (int nt = 0; nt < 6; ++nt)
#pragma unroll
        for (int r = 0; r < 4; ++r) {
            const int row = q0 + w * 16 + lg * 4 + r;
            const int col = h * DKD + nt * 16 + l15;
            Opart[((size_t)cch * TT + row) * D + col] = f2b(acc_o[nt][r]);
        }
    if (l15 == 0) {
#pragma unroll
        for (int r = 0; r < 4; ++r) {
            const int row = q0 + w * 16 + lg * 4 + r;
            float2* mlp = (float2*)ml;
            mlp[((size_t)cch * H + h) * TT + row] = make_float2(m_run[r], l_run[r]);
        }
    }
}

// ---------------- combine NS partials per row -------------------------------
__global__ __launch_bounds__(256) void attn_combine(const ushort_t* __restrict__ Opart,
        const float* __restrict__ ml, ushort_t* __restrict__ O) {
    const int row = blockIdx.x;
    const int tid = threadIdx.x;
    const float2* mlp = (const float2*)ml;
#pragma unroll
    for (int kk = 0; kk < 3; ++kk) {
        const int col = tid + kk * 256;
        const int h = col / DKD;
        float m[NS], l[NS], M = -1e30f;
#pragma unroll
        for (int c = 0; c < NS; ++c) {
            const float2 v = mlp[((size_t)c * H + h) * TT + row];
            m[c] = v.x; l[c] = v.y; M = fmaxf(M, m[c]);
        }
        float L = 0.f, o = 0.f;
#pragma unroll
        for (int c = 0; c < NS; ++c) {
            const float e = __expf(m[c] - M);
            L += l[c] * e;
            o += b2f(Opart[((size_t)c * TT + row) * D + col]) * e;
        }
        O[(size_t)row * D + col] = f2b(o / L);
    }
}

// ---------------- x = LN(x + y); writes fp32 x and bf16 xb ------------------
__global__ __launch_bounds__(256) void add_ln(float* __restrict__ x,
        const float* __restrict__ y, const float* __restrict__ g,
        const float* __restrict__ b, ushort_t* __restrict__ xb) {
    __shared__ float red[4];
    const int row = blockIdx.x;
    const int tid = threadIdx.x;
    float vals[3];
    float s = 0.f;
#pragma unroll
    for (int i = 0; i < 3; ++i) {
        const int c = tid + i * 256;
        const float t = x[(size_t)row * D + c] + y[(size_t)row * D + c];
        vals[i] = t; s += t;
    }
    const float mean = block_sum(s, red) * (1.f / 768.f);
    float s2 = 0.f;
#pragma unroll
    for (int i = 0; i < 3; ++i) { const float dd = vals[i] - mean; s2 += dd * dd; }
    const float var = block_sum(s2, red) * (1.f / 768.f);
    const float inv = rsqrtf(var + 1e-5f);
#pragma unroll
    for (int i = 0; i < 3; ++i) {
        const int c = tid + i * 256;
        const float o = (vals[i] - mean) * inv * g[c] + b[c];
        x[(size_t)row * D + c] = o;
        xb[(size_t)row * D + c] = f2b(o);
    }
}

// ---------------- predictor -------------------------------------------------
__global__ __launch_bounds__(256) void predict_k(const float* __restrict__ x,
        const float* __restrict__ pw, const float* __restrict__ pb,
        float* __restrict__ out) {
    __shared__ float red[4];
    const int r = blockIdx.x;
    const int tid = threadIdx.x;
    float best = -1e30f;
    for (int bag = 0; bag < BAG; ++bag) {
        const int row = (bag * SPANS) * E + (bag * SPANS + 1);
        const float* f = x + (size_t)row * D;
        float acc = 0.f;
        for (int d = tid; d < D; d += 256) acc += f[d] * pw[(size_t)d * NREL + r];
        best = fmaxf(best, block_sum(acc, red));
    }
    if (tid == 0) out[r] = best + pb[r];
}

extern "C" void kernel_launch(void* const* d_in, const int* in_sizes, int n_in,
                              void* d_out, int out_size, void* d_ws, size_t ws_size,
                              hipStream_t stream) {
    const float* emb  = (const float*)d_in[0];
    const int*  spans = (const int*)d_in[1];
    const float* wu_w = (const float*)d_in[2];  const float* wu_b = (const float*)d_in[3];
    const float* wvv_w= (const float*)d_in[4];  const float* wvv_b= (const float*)d_in[5];
    const float* lnr_w= (const float*)d_in[6];  const float* lnr_b= (const float*)d_in[7];
    const float* wq = (const float*)d_in[8];    const float* bq = (const float*)d_in[9];
    const float* wk = (const float*)d_in[10];   const float* bk = (const float*)d_in[11];
    const float* wv = (const float*)d_in[12];   const float* bv = (const float*)d_in[13];
    const float* wo = (const float*)d_in[14];   const float* bo = (const float*)d_in[15];
    const float* w1 = (const float*)d_in[16];   const float* b1 = (const float*)d_in[17];
    const float* w2 = (const float*)d_in[18];   const float* b2 = (const float*)d_in[19];
    const float* g1 = (const float*)d_in[20];   const float* be1= (const float*)d_in[21];
    const float* g2 = (const float*)d_in[22];   const float* be2= (const float*)d_in[23];
    const float* pw = (const float*)d_in[24];   const float* pb = (const float*)d_in[25];

    // workspace layout (~35 MB). tb/fb adjacency required (Opart alias).
    char* cur = (char*)d_ws;
    auto alloc = [&](size_t bytes) { char* p = cur; cur += (bytes + 255) & ~(size_t)255; return p; };
    ushort_t* htb  = (ushort_t*)alloc(E * D * 2);
    float*    uvb  = (float*)alloc((size_t)E * 1536 * 4);
    float*    part = (float*)alloc((size_t)E * 8 * D * 4);   // span partials; reused as ml
    float*    x    = (float*)alloc((size_t)TT * D * 4);
    ushort_t* xb   = (ushort_t*)alloc((size_t)TT * D * 2);
    ushort_t* qkb  = (ushort_t*)alloc((size_t)TT * D2 * 2);  // fused Q|K, ld=1536
    ushort_t* vTb  = (ushort_t*)alloc((size_t)D * TT * 2);   // V^T [768][1600]
    ushort_t* ob   = (ushort_t*)alloc((size_t)TT * D * 2);   // alpha, then attn out
    float*    tb   = (float*)alloc((size_t)TT * D * 4);      // adjacent ...
    ushort_t* fb   = (ushort_t*)alloc((size_t)TT * FFD * 2); // ... to tb
    ushort_t* wT4  = (ushort_t*)alloc((size_t)4 * D * D * 2);
    ushort_t* w1T  = (ushort_t*)alloc((size_t)D * FFD * 2);
    ushort_t* w2T  = (ushort_t*)alloc((size_t)FFD * D * 2);
    float*    bqk  = (float*)alloc((size_t)LAY * D2 * 4);
    float*    buv  = (float*)alloc((size_t)2 * D * 4);
    ushort_t* Opart = (ushort_t*)tb;    // NS*TT*D*2 = 7.37 MB <= tb+fb (8.2 MB)
    float*    ml    = part;             // 300 KB <= part
    ushort_t* wuvT  = wT4;              // [1536][768], used before layer 0
    ushort_t* lnrT  = w1T;              // [768][768], used before layer 0

    const int DD = D * D;

    span_pool_p1<<<dim3(E, 8), 256, 0, stream>>>(emb, spans, part);
    span_pool_p2<<<E, 256, 0, stream>>>(part, htb);
    transpose_up<<<dim3(24, 24, 3), 256, 0, stream>>>(lnr_w, wu_w, wvv_w, lnrT, wuvT);
    concat_bias<<<(LAY * D2 + 2 * D + 255) / 256, 256, 0, stream>>>(bq, bk, wu_b, wvv_b, bqk, buv);
    gemm_mfma<0, 0><<<dim3(1536 / 64, 1), 256, 0, stream>>>(htb, wuvT, buv, uvb, nullptr, E, 1536, D);
    alpha_k<<<TT, 256, 0, stream>>>(uvb, ob);
    gemm_mfma<1, 0><<<dim3(D / 64, (TT + 127) / 128), 256, 0, stream>>>(ob, lnrT, lnr_b, x, xb, TT, D, D);

    for (int l = 0; l < LAY; ++l) {
        transpose_layer<<<dim3(32, 32, 6), 256, 0, stream>>>(wq, wk, wv, wo, w1, w2, l, wT4, w1T, w2T);
        // fused Q|K projection: [1600,768] @ [1536,768]^T
        gemm_mfma<0, 0><<<dim3(D2 / 64, (TT + 127) / 128), 256, 0, stream>>>(
            xb, wT4, bqk + l * D2, nullptr, qkb, TT, D2, D);
        // V^T: swapped operands -> [768,1600], row bias
        gemm_mfma<0, 1><<<dim3(TT / 64, D / 128), 256, 0, stream>>>(
            wT4 + 2 * DD, xb, bv + l * D, nullptr, vTb, D, TT, D);
        attn_part<<<dim3(TT / 64, H, NS), 256, 0, stream>>>(qkb, vTb, Opart, ml);
        attn_combine<<<TT, 256, 0, stream>>>(Opart, ml, ob);
        gemm_mfma<0, 0><<<dim3(D / 64, (TT + 127) / 128), 256, 0, stream>>>(
            ob, wT4 + 3 * DD, bo + l * D, tb, nullptr, TT, D, D);
        add_ln<<<TT, 256, 0, stream>>>(x, tb, g1 + l * D, be1 + l * D, xb);
        gemm_mfma<1, 0><<<dim3(FFD / 64, (TT + 127) / 128), 256, 0, stream>>>(
            xb, w1T, b1 + l * FFD, nullptr, fb, TT, FFD, D);
        gemm_mfma<0, 0><<<dim3(D / 64, (TT + 127) / 128), 256, 0, stream>>>(
            fb, w2T, b2 + l * D, tb, nullptr, TT, D, FFD);
        add_ln<<<TT, 256, 0, stream>>>(x, tb, g2 + l * D, be2 + l * D, xb);
    }

    predict_k<<<NREL, 256, 0, stream>>>(x, pw, pb, (float*)d_out);
    (void)in_sizes; (void)n_in; (void)out_size; (void)ws_size;
}

// Round 7
// 762.428 us; speedup vs baseline: 1.0492x; 1.0114x over previous
//
#include <hip/hip_runtime.h>

// Codred forward. R6 (attention-focused):
//  - Opart head-major [cch][h][row][96]: per-block contiguous writes, kills the
//    10x HBM write amplification seen in R5's interleaved layout (70MB -> ~12MB)
//  - Q kept in registers (wave only needs its own 16 rows) -> -13.3KB LDS,
//    4 blocks/CU, one less staging phase
//  - defer-max rescale (T13, THR=8) with wave-uniform __any
//  - 1/sqrt(96) folded into Q at the QK-projection epilogue
//  - GEMM side unchanged from R5 (128x64, global_load_lds, fused transposes)

#define D    768
#define H    8
#define DKD  96
#define LAY  4
#define FFD  1024
#define NREL 97
#define BAG  8
#define SPANS 5
#define E    40
#define TT   1600
#define SEQ  512
#define D2   1536   // fused qk width
#define NS   3      // kv chunks

typedef __attribute__((ext_vector_type(8))) short bf16x8;
typedef __attribute__((ext_vector_type(4))) float f32x4;
typedef unsigned short ushort_t;
typedef unsigned int uint_t;

__device__ __forceinline__ ushort_t f2b(float x) {
    uint_t u = __builtin_bit_cast(uint_t, x);
    return (ushort_t)((u + 0x7fffu + ((u >> 16) & 1u)) >> 16);   // RNE
}
__device__ __forceinline__ float b2f(ushort_t v) {
    return __builtin_bit_cast(float, (uint_t)v << 16);
}

__device__ __forceinline__ void gload16(const void* g, void* l) {
    __builtin_amdgcn_global_load_lds(
        (const __attribute__((address_space(1))) unsigned int*)g,
        (__attribute__((address_space(3))) unsigned int*)l, 16, 0, 0);
}

// ---------------- block reductions (256 thr) --------------------------------
__device__ __forceinline__ float block_sum(float v, float* red) {
#pragma unroll
    for (int o = 32; o >= 1; o >>= 1) v += __shfl_xor(v, o);
    __syncthreads();
    if ((threadIdx.x & 63) == 0) red[threadIdx.x >> 6] = v;
    __syncthreads();
    return red[0] + red[1] + red[2] + red[3];
}

// ---------------- span max-pool, phase 1 ------------------------------------
__global__ __launch_bounds__(256) void span_pool_p1(const float* __restrict__ emb,
        const int* __restrict__ spans, float* __restrict__ partial) {
    const int e = blockIdx.x, pg = blockIdx.y;
    const int bag = e / SPANS;
    const int st = spans[e * 2 + 0];
    const int en = spans[e * 2 + 1];
    const int p0 = max(st, pg * 64);
    const int p1 = min(en, pg * 64 + 63);
    const int tid = threadIdx.x;
    if (tid >= 192) return;
    float4 m = make_float4(-1e30f, -1e30f, -1e30f, -1e30f);
    for (int p = p0; p <= p1; ++p) {
        const float4 v = *(const float4*)(emb + ((size_t)bag * SEQ + p) * D + tid * 4);
        m.x = fmaxf(m.x, v.x); m.y = fmaxf(m.y, v.y);
        m.z = fmaxf(m.z, v.z); m.w = fmaxf(m.w, v.w);
    }
    *(float4*)(partial + ((size_t)e * 8 + pg) * D + tid * 4) = m;
}

// ---------------- span max-pool, phase 2 -> bf16 htb ------------------------
__global__ __launch_bounds__(256) void span_pool_p2(const float* __restrict__ partial,
        ushort_t* __restrict__ htb) {
    const int e = blockIdx.x;
    const int tid = threadIdx.x;
    if (tid >= 192) return;
    float4 m = make_float4(-1e30f, -1e30f, -1e30f, -1e30f);
#pragma unroll
    for (int pg = 0; pg < 8; ++pg) {
        const float4 v = *(const float4*)(partial + ((size_t)e * 8 + pg) * D + tid * 4);
        m.x = fmaxf(m.x, v.x); m.y = fmaxf(m.y, v.y);
        m.z = fmaxf(m.z, v.z); m.w = fmaxf(m.w, v.w);
    }
    ushort4 o;
    o.x = f2b(m.x); o.y = f2b(m.y); o.z = f2b(m.z); o.w = f2b(m.w);
    *(ushort4*)(htb + (size_t)e * D + tid * 4) = o;
}

// ---------------- alpha: a[ij][d] = relu(u[i][d]+v[j][d]) (bf16 out) --------
__global__ __launch_bounds__(256) void alpha_k(const float* __restrict__ uv,
        ushort_t* __restrict__ a) {
    const int ij = blockIdx.x;
    const int i = ij / E, j = ij % E;
    const int tid = threadIdx.x;
#pragma unroll
    for (int t2 = 0; t2 < 3; ++t2) {
        const int d = tid + t2 * 256;
        a[(size_t)ij * D + d] =
            f2b(fmaxf(uv[(size_t)i * 1536 + d] + uv[(size_t)j * 1536 + 768 + d], 0.f));
    }
}

// ---------------- upfront transpose: z=0 lnr, z=1 wu, z=2 wvv ---------------
__global__ __launch_bounds__(256) void transpose_up(const float* __restrict__ lnr,
        const float* __restrict__ wu, const float* __restrict__ wvv,
        ushort_t* __restrict__ lnrT, ushort_t* __restrict__ wuvT) {
    __shared__ float t[32][33];
    const int z = blockIdx.z;
    const float* src = (z == 0) ? lnr : (z == 1) ? wu : wvv;
    ushort_t* dst = (z == 0) ? lnrT : wuvT + (size_t)(z - 1) * D * D;
    const int n0 = blockIdx.x * 32, k0 = blockIdx.y * 32;
    const int tx = threadIdx.x & 31, ty = threadIdx.x >> 5;
#pragma unroll
    for (int i = 0; i < 4; ++i)
        t[ty + i * 8][tx] = src[(size_t)(k0 + ty + i * 8) * D + n0 + tx];
    __syncthreads();
#pragma unroll
    for (int i = 0; i < 4; ++i)
        dst[(size_t)(n0 + ty + i * 8) * D + k0 + tx] = f2b(t[tx][ty + i * 8]);
}

// ---------------- per-layer fused transpose: z 0..3 wq/wk/wv/wo, 4 w1, 5 w2 -
__global__ __launch_bounds__(256) void transpose_layer(const float* __restrict__ wq,
        const float* __restrict__ wk, const float* __restrict__ wv,
        const float* __restrict__ wo, const float* __restrict__ w1,
        const float* __restrict__ w2, int l, ushort_t* __restrict__ wT4,
        ushort_t* __restrict__ w1T, ushort_t* __restrict__ w2T) {
    __shared__ float t[32][33];
    const int z = blockIdx.z;
    const float* src; ushort_t* dst; int K, N;
    if (z < 4) {
        K = D; N = D;
        src = (z == 0 ? wq : z == 1 ? wk : z == 2 ? wv : wo) + (size_t)l * D * D;
        dst = wT4 + (size_t)z * D * D;
    } else if (z == 4) {
        K = D; N = FFD; src = w1 + (size_t)l * D * FFD; dst = w1T;
    } else {
        K = FFD; N = D; src = w2 + (size_t)l * FFD * D; dst = w2T;
    }
    const int n0 = blockIdx.x * 32, k0 = blockIdx.y * 32;
    if (n0 >= N || k0 >= K) return;
    const int tx = threadIdx.x & 31, ty = threadIdx.x >> 5;
#pragma unroll
    for (int i = 0; i < 4; ++i)
        t[ty + i * 8][tx] = src[(size_t)(k0 + ty + i * 8) * N + n0 + tx];
    __syncthreads();
#pragma unroll
    for (int i = 0; i < 4; ++i)
        dst[(size_t)(n0 + ty + i * 8) * K + k0 + tx] = f2b(t[tx][ty + i * 8]);
}

// ---------------- biases: bqk [L][1536], buv [1536] --------------------------
__global__ __launch_bounds__(256) void concat_bias(const float* __restrict__ bq,
        const float* __restrict__ bk, const float* __restrict__ bu,
        const float* __restrict__ bvv, float* __restrict__ bqk,
        float* __restrict__ buv) {
    const int i = blockIdx.x * 256 + threadIdx.x;
    if (i < LAY * D2) {
        const int l = i / D2, j = i % D2;
        bqk[i] = j < D ? bq[l * D + j] : bk[l * D + j - D];
    }
    const int k = i - LAY * D2;
    if (k >= 0 && k < 2 * D) buv[k] = k < D ? bu[k] : bvv[k - D];
}

// ---------------- bf16 MFMA GEMM: C = A[M,K] @ Bt[N,K]^T + bias -------------
// 128x64 tile, BK=32, 4 waves (2x2), global_load_lds width=16.
// ROWBIAS: bias indexed by output row. SCALEQ: multiply cols<768 by 1/sqrt(96)
// after bias (folds the attention scale into Q at the QK projection).
template<int RELU, int ROWBIAS, int SCALEQ>
__global__ __launch_bounds__(256) void gemm_mfma(const ushort_t* __restrict__ A,
        const ushort_t* __restrict__ Bt, const float* __restrict__ bias,
        float* __restrict__ Cf, ushort_t* __restrict__ Cb, int M, int N, int K) {
    __shared__ ushort_t As[128 * 32];   // linear: row*32 + col
    __shared__ ushort_t Bs[64 * 32];
    const int tid = threadIdx.x;
    const int lane = tid & 63, w = tid >> 6;
    const int l15 = lane & 15, lg = lane >> 4;
    const int bm = blockIdx.y * 128, bn = blockIdx.x * 64;
    const int wm = (w >> 1) * 64, wn = (w & 1) * 32;
    const int trA0 = w * 32 + (lane >> 2);
    const int trA1 = trA0 + 16;
    const int trB  = w * 16 + (lane >> 2);
    const int sc   = (lane & 3) * 8;
    const size_t rowA0 = (size_t)min(bm + trA0, M - 1) * K;
    const size_t rowA1 = (size_t)min(bm + trA1, M - 1) * K;
    const size_t rowB  = (size_t)(bn + trB) * K;
    ushort_t* asd0 = As + w * 1024;
    ushort_t* asd1 = As + w * 1024 + 512;
    ushort_t* bsd  = Bs + w * 512;

    f32x4 acc[4][2];
#pragma unroll
    for (int mi = 0; mi < 4; ++mi)
#pragma unroll
        for (int ni = 0; ni < 2; ++ni)
            acc[mi][ni] = (f32x4){0.f, 0.f, 0.f, 0.f};

    for (int k0 = 0; k0 < K; k0 += 32) {
        __syncthreads();
        gload16(A + rowA0 + k0 + sc, asd0);
        gload16(A + rowA1 + k0 + sc, asd1);
        gload16(Bt + rowB + k0 + sc, bsd);
        __syncthreads();
        bf16x8 af[4], bfr[2];
#pragma unroll
        for (int mi = 0; mi < 4; ++mi)
            af[mi] = *(const bf16x8*)&As[(wm + mi * 16 + l15) * 32 + lg * 8];
#pragma unroll
        for (int ni = 0; ni < 2; ++ni)
            bfr[ni] = *(const bf16x8*)&Bs[(wn + ni * 16 + l15) * 32 + lg * 8];
        __builtin_amdgcn_s_setprio(1);
#pragma unroll
        for (int mi = 0; mi < 4; ++mi)
#pragma unroll
            for (int ni = 0; ni < 2; ++ni)
                acc[mi][ni] = __builtin_amdgcn_mfma_f32_16x16x32_bf16(
                    af[mi], bfr[ni], acc[mi][ni], 0, 0, 0);
        __builtin_amdgcn_s_setprio(0);
    }
#pragma unroll
    for (int mi = 0; mi < 4; ++mi)
#pragma unroll
        for (int ni = 0; ni < 2; ++ni)
#pragma unroll
            for (int r = 0; r < 4; ++r) {
                const int row = bm + wm + mi * 16 + lg * 4 + r;
                if (row >= M) continue;
                const int col = bn + wn + ni * 16 + l15;
                float v = acc[mi][ni][r] + (ROWBIAS ? bias[row] : bias[col]);
                if (RELU) v = fmaxf(v, 0.f);
                if (SCALEQ) { if (col < D) v *= 0.10206207261596577f; }
                if (Cf) Cf[(size_t)row * N + col] = v;
                if (Cb) Cb[(size_t)row * N + col] = f2b(v);
            }
}

// ---------------- flash-decoding attention over a KV chunk ------------------
// grid (25 qtiles, 8 heads, NS chunks); 4 waves, wave w owns 16 q-rows.
// Q pre-scaled by 1/sqrt(96), kept in REGISTERS; K from qk (ld=1536); V from
// vT [768][1600]. Opart head-major: [cch][h][row][96] (contiguous per block).
__global__ __launch_bounds__(256) void attn_part(const ushort_t* __restrict__ qk,
        const ushort_t* __restrict__ vT, ushort_t* __restrict__ Opart,
        float* __restrict__ ml) {
    __shared__ ushort_t Ks[64][104];     // 96 + 8 pad
    __shared__ ushort_t VtT[96][76];     // V^T tile: [dim][s]
    __shared__ ushort_t Ps[4][16][72];   // per-wave P tile
    const int q0 = blockIdx.x * 64;
    const int h = blockIdx.y;
    const int cch = blockIdx.z;
    const int t_lo = (cch * (TT / 64)) / NS;
    const int t_hi = ((cch + 1) * (TT / 64)) / NS;
    const int tid = threadIdx.x;
    const int lane = tid & 63, w = tid >> 6;
    const int l15 = lane & 15, lg = lane >> 4;

    const ushort_t* Vb = vT + (size_t)h * DKD * TT;

    // chunk coords: K tiles 64 rows x 96 dims; V^T tiles 96 dims x 64 s
    int r_[3], c_[3], vd_[3], vs_[3];
#pragma unroll
    for (int i = 0; i < 3; ++i) {
        const int ch = i * 256 + tid;
        r_[i] = ch / 12; c_[i] = (ch % 12) * 8;
        vd_[i] = ch >> 3; vs_[i] = (ch & 7) * 8;
    }
    // Q fragments in registers (wave w uses only rows q0+w*16+l15)
    bf16x8 qfrag[3];
#pragma unroll
    for (int ks = 0; ks < 3; ++ks)
        qfrag[ks] = *(const bf16x8*)(qk + (size_t)(q0 + w * 16 + l15) * D2
                                     + h * DKD + ks * 32 + lg * 8);
    // prologue: first K/V^T tile into regs
    uint4 kreg[3], vreg[3];
    {
        const int s0 = t_lo * 64;
#pragma unroll
        for (int i = 0; i < 3; ++i) {
            kreg[i] = *(const uint4*)(qk + (size_t)(s0 + r_[i]) * D2 + D + h * DKD + c_[i]);
            vreg[i] = *(const uint4*)(Vb + (size_t)vd_[i] * TT + s0 + vs_[i]);
        }
    }
    float m_run[4], l_run[4];
    f32x4 acc_o[6];
#pragma unroll
    for (int r = 0; r < 4; ++r) { m_run[r] = -1e30f; l_run[r] = 0.f; }
#pragma unroll
    for (int nt = 0; nt < 6; ++nt) acc_o[nt] = (f32x4){0.f, 0.f, 0.f, 0.f};

    for (int t = t_lo; t < t_hi; ++t) {
        __syncthreads();
#pragma unroll
        for (int i = 0; i < 3; ++i) {
            *(uint4*)&Ks[r_[i]][c_[i]] = kreg[i];
            *(uint4*)&VtT[vd_[i]][vs_[i]] = vreg[i];
        }
        __syncthreads();
        if (t + 1 < t_hi) {            // issue next-tile loads early (T14)
            const int s0 = (t + 1) * 64;
#pragma unroll
            for (int i = 0; i < 3; ++i) {
                kreg[i] = *(const uint4*)(qk + (size_t)(s0 + r_[i]) * D2 + D + h * DKD + c_[i]);
                vreg[i] = *(const uint4*)(Vb + (size_t)vd_[i] * TT + s0 + vs_[i]);
            }
        }
        // S = Q K^T (Q pre-scaled)
        f32x4 accs[4];
#pragma unroll
        for (int ni = 0; ni < 4; ++ni) accs[ni] = (f32x4){0.f, 0.f, 0.f, 0.f};
        __builtin_amdgcn_s_setprio(1);
#pragma unroll
        for (int ks = 0; ks < 3; ++ks) {
#pragma unroll
            for (int ni = 0; ni < 4; ++ni) {
                const bf16x8 bk = *(const bf16x8*)&Ks[ni * 16 + l15][ks * 32 + lg * 8];
                accs[ni] = __builtin_amdgcn_mfma_f32_16x16x32_bf16(qfrag[ks], bk, accs[ni], 0, 0, 0);
            }
        }
        __builtin_amdgcn_s_setprio(0);
        // online softmax with defer-max (T13, THR=8)
        float mx[4];
#pragma unroll
        for (int r = 0; r < 4; ++r) {
            mx[r] = fmaxf(fmaxf(accs[0][r], accs[1][r]), fmaxf(accs[2][r], accs[3][r]));
#pragma unroll
            for (int o = 1; o <= 8; o <<= 1) mx[r] = fmaxf(mx[r], __shfl_xor(mx[r], o));
        }
        const bool grow = (mx[0] > m_run[0] + 8.f) || (mx[1] > m_run[1] + 8.f) ||
                          (mx[2] > m_run[2] + 8.f) || (mx[3] > m_run[3] + 8.f);
        if (__any(grow)) {
#pragma unroll
            for (int r = 0; r < 4; ++r) {
                const float mnew = fmaxf(m_run[r], mx[r]);
                const float sf = __expf(m_run[r] - mnew);
                m_run[r] = mnew;
                l_run[r] *= sf;
#pragma unroll
                for (int nt = 0; nt < 6; ++nt) acc_o[nt][r] *= sf;
            }
        }
        float ps[4][4];
#pragma unroll
        for (int r = 0; r < 4; ++r) {
            float rs = 0.f;
#pragma unroll
            for (int ni = 0; ni < 4; ++ni) {
                ps[ni][r] = __expf(accs[ni][r] - m_run[r]);
                rs += ps[ni][r];
            }
#pragma unroll
            for (int o = 1; o <= 8; o <<= 1) rs += __shfl_xor(rs, o);
            l_run[r] += rs;
        }
#pragma unroll
        for (int ni = 0; ni < 4; ++ni)
#pragma unroll
            for (int r = 0; r < 4; ++r)
                Ps[w][lg * 4 + r][ni * 16 + l15] = f2b(ps[ni][r]);
        // O += P @ V
        __builtin_amdgcn_s_setprio(1);
#pragma unroll
        for (int ks = 0; ks < 2; ++ks) {
            const bf16x8 ap = *(const bf16x8*)&Ps[w][l15][ks * 32 + lg * 8];
#pragma unroll
            for (int nt = 0; nt < 6; ++nt) {
                const bf16x8 bv = *(const bf16x8*)&VtT[nt * 16 + l15][ks * 32 + lg * 8];
                acc_o[nt] = __builtin_amdgcn_mfma_f32_16x16x32_bf16(ap, bv, acc_o[nt], 0, 0, 0);
            }
        }
        __builtin_amdgcn_s_setprio(0);
    }
    // epilogue: unnormalized O (head-major, per-block contiguous) + (m,l)
#pragma unroll
    for (int nt = 0; nt < 6; ++nt)
#pragma unroll
        for (int r = 0; r < 4; ++r) {
            const int row = q0 + w * 16 + lg * 4 + r;
            Opart[(((size_t)cch * H + h) * TT + row) * DKD + nt * 16 + l15] =
                f2b(acc_o[nt][r]);
        }
    if (l15 == 0) {
#pragma unroll
        for (int r = 0; r < 4; ++r) {
            const int row = q0 + w * 16 + lg * 4 + r;
            float2* mlp = (float2*)ml;
            mlp[((size_t)cch * H + h) * TT + row] = make_float2(m_run[r], l_run[r]);
        }
    }
}

// ---------------- combine NS partials per row -------------------------------
__global__ __launch_bounds__(256) void attn_combine(const ushort_t* __restrict__ Opart,
        const float* __restrict__ ml, ushort_t* __restrict__ O) {
    const int row = blockIdx.x;
    const int tid = threadIdx.x;
    const float2* mlp = (const float2*)ml;
#pragma unroll
    for (int kk = 0; kk < 3; ++kk) {
        const int col = tid + kk * 256;
        const int h = col / DKD, d = col % DKD;
        float m[NS], l[NS], M = -1e30f;
#pragma unroll
        for (int c = 0; c < NS; ++c) {
            const float2 v = mlp[((size_t)c * H + h) * TT + row];
            m[c] = v.x; l[c] = v.y; M = fmaxf(M, m[c]);
        }
        float L = 0.f, o = 0.f;
#pragma unroll
        for (int c = 0; c < NS; ++c) {
            const float e = __expf(m[c] - M);
            L += l[c] * e;
            o += b2f(Opart[(((size_t)c * H + h) * TT + row) * DKD + d]) * e;
        }
        O[(size_t)row * D + col] = f2b(o / L);
    }
}

// ---------------- x = LN(x + y); writes fp32 x and bf16 xb ------------------
__global__ __launch_bounds__(256) void add_ln(float* __restrict__ x,
        const float* __restrict__ y, const float* __restrict__ g,
        const float* __restrict__ b, ushort_t* __restrict__ xb) {
    __shared__ float red[4];
    const int row = blockIdx.x;
    const int tid = threadIdx.x;
    float vals[3];
    float s = 0.f;
#pragma unroll
    for (int i = 0; i < 3; ++i) {
        const int c = tid + i * 256;
        const float t = x[(size_t)row * D + c] + y[(size_t)row * D + c];
        vals[i] = t; s += t;
    }
    const float mean = block_sum(s, red) * (1.f / 768.f);
    float s2 = 0.f;
#pragma unroll
    for (int i = 0; i < 3; ++i) { const float dd = vals[i] - mean; s2 += dd * dd; }
    const float var = block_sum(s2, red) * (1.f / 768.f);
    const float inv = rsqrtf(var + 1e-5f);
#pragma unroll
    for (int i = 0; i < 3; ++i) {
        const int c = tid + i * 256;
        const float o = (vals[i] - mean) * inv * g[c] + b[c];
        x[(size_t)row * D + c] = o;
        xb[(size_t)row * D + c] = f2b(o);
    }
}

// ---------------- predictor -------------------------------------------------
__global__ __launch_bounds__(256) void predict_k(const float* __restrict__ x,
        const float* __restrict__ pw, const float* __restrict__ pb,
        float* __restrict__ out) {
    __shared__ float red[4];
    const int r = blockIdx.x;
    const int tid = threadIdx.x;
    float best = -1e30f;
    for (int bag = 0; bag < BAG; ++bag) {
        const int row = (bag * SPANS) * E + (bag * SPANS + 1);
        const float* f = x + (size_t)row * D;
        float acc = 0.f;
        for (int d = tid; d < D; d += 256) acc += f[d] * pw[(size_t)d * NREL + r];
        best = fmaxf(best, block_sum(acc, red));
    }
    if (tid == 0) out[r] = best + pb[r];
}

extern "C" void kernel_launch(void* const* d_in, const int* in_sizes, int n_in,
                              void* d_out, int out_size, void* d_ws, size_t ws_size,
                              hipStream_t stream) {
    const float* emb  = (const float*)d_in[0];
    const int*  spans = (const int*)d_in[1];
    const float* wu_w = (const float*)d_in[2];  const float* wu_b = (const float*)d_in[3];
    const float* wvv_w= (const float*)d_in[4];  const float* wvv_b= (const float*)d_in[5];
    const float* lnr_w= (const float*)d_in[6];  const float* lnr_b= (const float*)d_in[7];
    const float* wq = (const float*)d_in[8];    const float* bq = (const float*)d_in[9];
    const float* wk = (const float*)d_in[10];   const float* bk = (const float*)d_in[11];
    const float* wv = (const float*)d_in[12];   const float* bv = (const float*)d_in[13];
    const float* wo = (const float*)d_in[14];   const float* bo = (const float*)d_in[15];
    const float* w1 = (const float*)d_in[16];   const float* b1 = (const float*)d_in[17];
    const float* w2 = (const float*)d_in[18];   const float* b2 = (const float*)d_in[19];
    const float* g1 = (const float*)d_in[20];   const float* be1= (const float*)d_in[21];
    const float* g2 = (const float*)d_in[22];   const float* be2= (const float*)d_in[23];
    const float* pw = (const float*)d_in[24];   const float* pb = (const float*)d_in[25];

    // workspace layout (~35 MB). tb/fb adjacency required (Opart alias).
    char* cur = (char*)d_ws;
    auto alloc = [&](size_t bytes) { char* p = cur; cur += (bytes + 255) & ~(size_t)255; return p; };
    ushort_t* htb  = (ushort_t*)alloc(E * D * 2);
    float*    uvb  = (float*)alloc((size_t)E * 1536 * 4);
    float*    part = (float*)alloc((size_t)E * 8 * D * 4);   // span partials; reused as ml
    float*    x    = (float*)alloc((size_t)TT * D * 4);
    ushort_t* xb   = (ushort_t*)alloc((size_t)TT * D * 2);
    ushort_t* qkb  = (ushort_t*)alloc((size_t)TT * D2 * 2);  // fused Q|K, ld=1536
    ushort_t* vTb  = (ushort_t*)alloc((size_t)D * TT * 2);   // V^T [768][1600]
    ushort_t* ob   = (ushort_t*)alloc((size_t)TT * D * 2);   // alpha, then attn out
    float*    tb   = (float*)alloc((size_t)TT * D * 4);      // adjacent ...
    ushort_t* fb   = (ushort_t*)alloc((size_t)TT * FFD * 2); // ... to tb
    ushort_t* wT4  = (ushort_t*)alloc((size_t)4 * D * D * 2);
    ushort_t* w1T  = (ushort_t*)alloc((size_t)D * FFD * 2);
    ushort_t* w2T  = (ushort_t*)alloc((size_t)FFD * D * 2);
    float*    bqk  = (float*)alloc((size_t)LAY * D2 * 4);
    float*    buv  = (float*)alloc((size_t)2 * D * 4);
    ushort_t* Opart = (ushort_t*)tb;    // NS*H*TT*DKD*2 = 7.37 MB <= tb+fb (8.2 MB)
    float*    ml    = part;             // 300 KB <= part
    ushort_t* wuvT  = wT4;              // [1536][768], used before layer 0
    ushort_t* lnrT  = w1T;              // [768][768], used before layer 0

    const int DD = D * D;

    span_pool_p1<<<dim3(E, 8), 256, 0, stream>>>(emb, spans, part);
    span_pool_p2<<<E, 256, 0, stream>>>(part, htb);
    transpose_up<<<dim3(24, 24, 3), 256, 0, stream>>>(lnr_w, wu_w, wvv_w, lnrT, wuvT);
    concat_bias<<<(LAY * D2 + 2 * D + 255) / 256, 256, 0, stream>>>(bq, bk, wu_b, wvv_b, bqk, buv);
    gemm_mfma<0, 0, 0><<<dim3(1536 / 64, 1), 256, 0, stream>>>(htb, wuvT, buv, uvb, nullptr, E, 1536, D);
    alpha_k<<<TT, 256, 0, stream>>>(uvb, ob);
    gemm_mfma<1, 0, 0><<<dim3(D / 64, (TT + 127) / 128), 256, 0, stream>>>(ob, lnrT, lnr_b, x, xb, TT, D, D);

    for (int l = 0; l < LAY; ++l) {
        transpose_layer<<<dim3(32, 32, 6), 256, 0, stream>>>(wq, wk, wv, wo, w1, w2, l, wT4, w1T, w2T);
        // fused Q|K projection (Q cols pre-scaled by 1/sqrt(96))
        gemm_mfma<0, 0, 1><<<dim3(D2 / 64, (TT + 127) / 128), 256, 0, stream>>>(
            xb, wT4, bqk + l * D2, nullptr, qkb, TT, D2, D);
        // V^T: swapped operands -> [768,1600], row bias
        gemm_mfma<0, 1, 0><<<dim3(TT / 64, D / 128), 256, 0, stream>>>(
            wT4 + 2 * DD, xb, bv + l * D, nullptr, vTb, D, TT, D);
        attn_part<<<dim3(TT / 64, H, NS), 256, 0, stream>>>(qkb, vTb, Opart, ml);
        attn_combine<<<TT, 256, 0, stream>>>(Opart, ml, ob);
        gemm_mfma<0, 0, 0><<<dim3(D / 64, (TT + 127) / 128), 256, 0, stream>>>(
            ob, wT4 + 3 * DD, bo + l * D, tb, nullptr, TT, D, D);
        add_ln<<<TT, 256, 0, stream>>>(x, tb, g1 + l * D, be1 + l * D, xb);
        gemm_mfma<1, 0, 0><<<dim3(FFD / 64, (TT + 127) / 128), 256, 0, stream>>>(
            xb, w1T, b1 + l * FFD, nullptr, fb, TT, FFD, D);
        gemm_mfma<0, 0, 0><<<dim3(D / 64, (TT + 127) / 128), 256, 0, stream>>>(
            fb, w2T, b2 + l * D, tb, nullptr, TT, D, FFD);
        add_ln<<<TT, 256, 0, stream>>>(x, tb, g2 + l * D, be2 + l * D, xb);
    }

    predict_k<<<NREL, 256, 0, stream>>>(x, pw, pb, (float*)d_out);
    (void)in_sizes; (void)n_in; (void)out_size; (void)ws_size;
}